// Round 3
// baseline (310.844 us; speedup 1.0000x reference)
//
#include <hip/hip_runtime.h>
#include <stdint.h>

// MultiHeadedAttention: B=2,S=2048,D=1024,H=16,DK=64
// Pipeline: f32->f16 cvt; QKV proj GEMMs (MFMA f16, Q pre-scaled by
// 0.125*log2e); flash attention (swapped QK^T so q-row is lane-local:
// in-register softmax, float4 bias loads, b64 P writes); out proj -> f32.

typedef _Float16 f16;
typedef _Float16 f16x8 __attribute__((ext_vector_type(8)));
typedef _Float16 f16x4 __attribute__((ext_vector_type(4)));
typedef float f32x4 __attribute__((ext_vector_type(4)));

#define LOG2E 1.44269504088896340736f

__device__ __forceinline__ void gload16(const void* g, void* l) {
  __builtin_amdgcn_global_load_lds(
      (const __attribute__((address_space(1))) unsigned int*)g,
      (__attribute__((address_space(3))) unsigned int*)l, 16, 0, 0);
}

// ---------------- f32 -> f16 conversion (4 elems/thread, exact grid) ------
__global__ __launch_bounds__(256) void cvt_f32_f16(const float* __restrict__ in,
                                                   f16* __restrict__ out, int n4) {
  const int i = blockIdx.x * 256 + threadIdx.x;
  if (i >= n4) return;
  const float4 v = ((const float4*)in)[i];
  f16x4 o = {(f16)v.x, (f16)v.y, (f16)v.z, (f16)v.w};
  ((f16x4*)out)[i] = o;
}

// ---------------- mask dtype classify + canonicalize to u8 ----------------
__global__ void mask_detect(const uint8_t* __restrict__ m, int* __restrict__ flag) {
  __shared__ int s_off, s_weird;
  const int t = threadIdx.x;
  if (t == 0) { s_off = 0; s_weird = 0; }
  __syncthreads();
  int f_off = 0, f_weird = 0;
  for (int i = t; i < 8192; i += 256) {
    const uint8_t v = m[i];
    if ((i & 3) && v) f_off = 1;
    if (v > 1) f_weird = 1;
  }
  if (f_off) atomicOr(&s_off, 1);
  if (f_weird) atomicOr(&s_weird, 1);
  __syncthreads();
  if (t == 0) *flag = (s_off && !s_weird) ? 1 : 0;  // 1 => byte-sized bool
}

__global__ __launch_bounds__(256) void mask_canon(const uint8_t* __restrict__ m,
                                                  uint8_t* __restrict__ out,
                                                  const int* __restrict__ flag) {
  const int i = (blockIdx.x * 256 + threadIdx.x) * 4;  // grid covers 8388608
  uchar4 o;
  if (*flag) {
    const uchar4 v = *(const uchar4*)(m + i);
    o = make_uchar4(v.x != 0, v.y != 0, v.z != 0, v.w != 0);
  } else {
    const int4 v = *(const int4*)((const int*)m + i);
    o = make_uchar4(v.x != 0, v.y != 0, v.z != 0, v.w != 0);
  }
  *(uchar4*)(out + i) = o;
}

// ---------------- GEMM: C[m,n] = (sum_k A[m,k]*B[n,k] + bias[n])*scale ----
// MODE 0: f16 out [B,H,S,DK]; MODE 1: f16 out [B,H,DK,S]; MODE 2: f32 [M,N]
template <int MODE>
__global__ __launch_bounds__(256, 2) void gemm_bt(const f16* __restrict__ A,
                                                  const f16* __restrict__ Bw,
                                                  const float* __restrict__ bias,
                                                  void* __restrict__ outp,
                                                  float scale) {
  constexpr int K = 1024;
  const int t = threadIdx.x;
  const int w = t >> 6, lane = t & 63, l15 = lane & 15, l4 = lane >> 4;
  const int bm = (int)(blockIdx.x >> 4) * 128;
  const int bn = (int)(blockIdx.x & 15) * 64;

  __shared__ f16 As[2][128 * 32];
  __shared__ f16 Bs[2][64 * 32];

  const f16* a0 = A + (size_t)(bm + (t >> 2)) * K + (t & 3) * 8;
  const f16* a1 = a0 + (size_t)64 * K;
  const f16* b0 = Bw + (size_t)(bn + (t >> 2)) * K + (t & 3) * 8;

  f32x4 acc[2][4];
#pragma unroll
  for (int m = 0; m < 2; ++m)
#pragma unroll
    for (int n = 0; n < 4; ++n) acc[m][n] = (f32x4){0.f, 0.f, 0.f, 0.f};

#define STAGE_G(buf, k0)                          \
  do {                                            \
    gload16(a0 + (k0), &As[buf][w * 512]);        \
    gload16(a1 + (k0), &As[buf][2048 + w * 512]); \
    gload16(b0 + (k0), &Bs[buf][w * 512]);        \
  } while (0)

  STAGE_G(0, 0);
  __syncthreads();
  int cur = 0;
#pragma unroll 1
  for (int kt = 0; kt < 32; ++kt) {
    if (kt < 31) STAGE_G(cur ^ 1, (kt + 1) * 32);
    const f16* ap = &As[cur][(w * 32 + l15) * 32 + l4 * 8];
    const f16* bp = &Bs[cur][l15 * 32 + l4 * 8];
    f16x8 af[2], bfr[4];
#pragma unroll
    for (int m = 0; m < 2; ++m) af[m] = *(const f16x8*)(ap + m * 512);
#pragma unroll
    for (int n = 0; n < 4; ++n) bfr[n] = *(const f16x8*)(bp + n * 512);
#pragma unroll
    for (int m = 0; m < 2; ++m)
#pragma unroll
      for (int n = 0; n < 4; ++n)
        acc[m][n] = __builtin_amdgcn_mfma_f32_16x16x32_f16(af[m], bfr[n], acc[m][n], 0, 0, 0);
    __syncthreads();
    cur ^= 1;
  }
#undef STAGE_G

#pragma unroll
  for (int m = 0; m < 2; ++m) {
    const int r0 = bm + w * 32 + m * 16 + (l4 << 2);
#pragma unroll
    for (int n = 0; n < 4; ++n) {
      const int c = bn + n * 16 + l15;
      const float bv = bias[c];
#pragma unroll
      for (int j = 0; j < 4; ++j) {
        const int r = r0 + j;
        const float v = (acc[m][n][j] + bv) * scale;
        if (MODE == 0) {
          const int b_ = r >> 11, s = r & 2047, h_ = c >> 6, dk = c & 63;
          ((f16*)outp)[(((size_t)b_ * 16 + h_) * 2048 + s) * 64 + dk] = (f16)v;
        } else if (MODE == 1) {
          const int b_ = r >> 11, s = r & 2047, h_ = c >> 6, dk = c & 63;
          ((f16*)outp)[(((size_t)b_ * 16 + h_) * 64 + dk) * 2048 + s] = (f16)v;
        } else {
          ((float*)outp)[(size_t)r * 1024 + c] = v;
        }
      }
    }
  }
}

// ---------------- flash attention (swapped QK^T) --------------------------
// 1024 blocks: bid -> (qt 0..31, b, h). 4 waves x 16 q-rows, kv tile 64,
// K/V LDS double-buffered (one barrier/tile). Swapped mfma(K,Q): lane owns
// q = q0 + (lane&15); its 16 k-scores live in sacc regs -> in-register
// softmax (2 shfl_xor per reduce), float4 bias + u32 mask loads (prefetched
// one tile ahead), P packed to LDS via 4x ds_write_b64.
__device__ __forceinline__ const f16x8* swzr(const f16* base, int row, int bytecol) {
  return (const f16x8*)((const char*)base + row * 128 + (bytecol ^ ((row & 7) << 4)));
}

__global__ __launch_bounds__(256, 4) void attn_fwd(
    const f16* __restrict__ Qp, const f16* __restrict__ Kp,
    const f16* __restrict__ Vt, const float* __restrict__ bias,
    const uint8_t* __restrict__ mask, f16* __restrict__ X) {
  constexpr int S = 2048;
  const int bid = blockIdx.x;
  const int qt = bid & 31, b = (bid >> 5) & 1, h = bid >> 6;
  const int t = threadIdx.x, w = t >> 6, lane = t & 63;
  const int l15 = lane & 15, l4 = lane >> 4;
  const int q0 = qt * 64 + w * 16;

  const f16* Qbh = Qp + (size_t)(b * 16 + h) * S * 64;
  const f16* Kbh = Kp + (size_t)(b * 16 + h) * S * 64;
  const f16* Vbh = Vt + (size_t)(b * 16 + h) * 64 * S;
  // per-lane row pointers for q = q0 + l15, 16B chunk l4
  const float* biasr = bias + (size_t)h * S * S + (size_t)(q0 + l15) * S + l4 * 4;
  const uint8_t* maskr = mask + (size_t)b * S * S + (size_t)(q0 + l15) * S + l4 * 4;

  __shared__ f16 Ks[2][64 * 64];   // [kv][dk], swizzled
  __shared__ f16 Vs[2][64 * 64];   // [dk][kv], swizzled
  __shared__ f16 Ps[4][16 * 64];   // per-wave P [q][k], swizzled

  // Q B-frag: row = q = l15, k = ks*32 + l4*8 + i (Q pre-scaled by 0.125*log2e)
  f16x8 qf[2];
#pragma unroll
  for (int ks = 0; ks < 2; ++ks)
    qf[ks] = *(const f16x8*)(Qbh + (size_t)(q0 + l15) * 64 + ks * 32 + l4 * 8);

  f32x4 oacc[4];  // O[q = q0+l4*4+j, d = n*16+l15]
#pragma unroll
  for (int n = 0; n < 4; ++n) oacc[n] = (f32x4){0.f, 0.f, 0.f, 0.f};
  float mrow = -3e38f, lrow = 0.f;  // stats for q = q0 + l15 (replicated per l4)

  const int srow = t >> 3;
  const int scol = (((t & 7) ^ (srow & 7)) << 3);

#define STAGE(bf, kk)                                                              \
  do {                                                                             \
    gload16(Kbh + (size_t)((kk) + srow) * 64 + scol, &Ks[bf][w * 512]);            \
    gload16(Kbh + (size_t)((kk) + 32 + srow) * 64 + scol, &Ks[bf][2048 + w * 512]);\
    gload16(Vbh + (size_t)srow * S + (kk) + scol, &Vs[bf][w * 512]);               \
    gload16(Vbh + (size_t)(32 + srow) * S + (kk) + scol, &Vs[bf][2048 + w * 512]); \
  } while (0)

  STAGE(0, 0);
  f32x4 bcur[4];
  uint32_t mcur[4];
#pragma unroll
  for (int n = 0; n < 4; ++n) {
    bcur[n] = *(const f32x4*)(biasr + n * 16);
    mcur[n] = *(const uint32_t*)(maskr + n * 16);
  }
  __syncthreads();  // vmcnt(0): tile 0 + bias/mask regs ready

  int buf = 0;
#pragma unroll 1
  for (int kt = 0; kt < 32; ++kt) {
    const int k0 = kt * 64;
    f32x4 bnxt[4];
    uint32_t mnxt[4];
    if (kt < 31) {
      STAGE(buf ^ 1, k0 + 64);  // lands during this tile's compute
#pragma unroll
      for (int n = 0; n < 4; ++n) {
        bnxt[n] = *(const f32x4*)(biasr + k0 + 64 + n * 16);
        mnxt[n] = *(const uint32_t*)(maskr + k0 + 64 + n * 16);
      }
    }

    // ---- scores (swapped): sacc[n][j] = s(q=q0+l15, k=k0+16n+4*l4+j) ----
    f32x4 sacc[4];
#pragma unroll
    for (int n = 0; n < 4; ++n) sacc[n] = (f32x4){0.f, 0.f, 0.f, 0.f};
#pragma unroll
    for (int n = 0; n < 4; ++n)
#pragma unroll
      for (int ks = 0; ks < 2; ++ks) {
        const f16x8 kf = *swzr(&Ks[buf][0], n * 16 + l15, ks * 64 + l4 * 16);
        sacc[n] = __builtin_amdgcn_mfma_f32_16x16x32_f16(kf, qf[ks], sacc[n], 0, 0, 0);
      }

    // ---- bias + mask (log2e domain), in-register row max ----
    float tmax = -3e38f;
#pragma unroll
    for (int n = 0; n < 4; ++n)
#pragma unroll
      for (int j = 0; j < 4; ++j) {
        float s = fmaf(bcur[n][j], LOG2E, sacc[n][j]);
        s = ((mcur[n] >> (8 * j)) & 255u) ? -1.44269504e9f : s;
        sacc[n][j] = s;
        tmax = fmaxf(tmax, s);
      }
    tmax = fmaxf(tmax, __shfl_xor(tmax, 16));
    tmax = fmaxf(tmax, __shfl_xor(tmax, 32));

    // ---- online softmax (per-lane scalars) ----
    const float mnew = fmaxf(mrow, tmax);
    const float alpha = __builtin_exp2f(mrow - mnew);
    mrow = mnew;
    float lsum = 0.f;
#pragma unroll
    for (int n = 0; n < 4; ++n)
#pragma unroll
      for (int j = 0; j < 4; ++j) {
        const float e = __builtin_exp2f(sacc[n][j] - mnew);
        sacc[n][j] = e;
        lsum += e;
      }
    lsum += __shfl_xor(lsum, 16);
    lsum += __shfl_xor(lsum, 32);
    lrow = lrow * alpha + lsum;

    // ---- rescale O by alpha of its q = q0+l4*4+j (broadcast from lane) ----
    float aq[4];
#pragma unroll
    for (int j = 0; j < 4; ++j) aq[j] = __shfl(alpha, l4 * 4 + j);
#pragma unroll
    for (int n = 0; n < 4; ++n)
#pragma unroll
      for (int j = 0; j < 4; ++j) oacc[n][j] *= aq[j];

    // ---- P -> LDS (packed f16x4, swizzled) ----
#pragma unroll
    for (int n = 0; n < 4; ++n) {
      f16x4 pk = {(f16)sacc[n][0], (f16)sacc[n][1], (f16)sacc[n][2], (f16)sacc[n][3]};
      *(f16x4*)((char*)&Ps[w][0] + l15 * 128 +
                ((32 * n + 8 * l4) ^ ((l15 & 7) << 4))) = pk;
    }

    // ---- O += P.V ----
    f16x8 pf[2];
#pragma unroll
    for (int ks = 0; ks < 2; ++ks) pf[ks] = *swzr(&Ps[w][0], l15, ks * 64 + l4 * 16);
#pragma unroll
    for (int ks = 0; ks < 2; ++ks)
#pragma unroll
      for (int n = 0; n < 4; ++n) {
        const f16x8 vf = *swzr(&Vs[buf][0], n * 16 + l15, ks * 64 + l4 * 16);
        oacc[n] = __builtin_amdgcn_mfma_f32_16x16x32_f16(pf[ks], vf, oacc[n], 0, 0, 0);
      }

    __syncthreads();  // drains vmcnt: next tile staged; all waves done with buf
    buf ^= 1;
    if (kt < 31) {
#pragma unroll
      for (int n = 0; n < 4; ++n) { bcur[n] = bnxt[n]; mcur[n] = mnxt[n]; }
    }
  }
#undef STAGE

  // ---- normalize and store X[b,s,h*64+d] (f16) ----
  const float inv = 1.0f / lrow;
  float invq[4];
#pragma unroll
  for (int j = 0; j < 4; ++j) invq[j] = __shfl(inv, l4 * 4 + j);
#pragma unroll
  for (int j = 0; j < 4; ++j) {
    const int qrow = q0 + l4 * 4 + j;
#pragma unroll
    for (int n = 0; n < 4; ++n)
      X[((size_t)b * 2048 + qrow) * 1024 + h * 64 + n * 16 + l15] =
          (f16)(oacc[n][j] * invq[j]);
  }
}

// ---------------- host ------------------------------------------------------
extern "C" void kernel_launch(void* const* d_in, const int* in_sizes, int n_in,
                              void* d_out, int out_size, void* d_ws, size_t ws_size,
                              hipStream_t stream) {
  const float* query = (const float*)d_in[0];
  const float* key_ = (const float*)d_in[1];
  const float* value = (const float*)d_in[2];
  const uint8_t* mask = (const uint8_t*)d_in[3];
  const float* bias = (const float*)d_in[4];
  const float* Wq = (const float*)d_in[5];
  const float* bq = (const float*)d_in[6];
  const float* Wk = (const float*)d_in[7];
  const float* bk = (const float*)d_in[8];
  const float* Wv = (const float*)d_in[9];
  const float* bv = (const float*)d_in[10];
  const float* Wo = (const float*)d_in[11];
  const float* bo = (const float*)d_in[12];

  char* p = (char*)d_ws;
  f16* qh = (f16*)p; p += (size_t)4194304 * 2;
  f16* kh = (f16*)p; p += (size_t)4194304 * 2;
  f16* vh = (f16*)p; p += (size_t)4194304 * 2;
  f16* wqh = (f16*)p; p += (size_t)1048576 * 2;
  f16* wkh = (f16*)p; p += (size_t)1048576 * 2;
  f16* wvh = (f16*)p; p += (size_t)1048576 * 2;
  f16* woh = (f16*)p; p += (size_t)1048576 * 2;
  f16* Qp = (f16*)p; p += (size_t)4194304 * 2;
  f16* Kp = (f16*)p; p += (size_t)4194304 * 2;
  f16* Vt = (f16*)p; p += (size_t)4194304 * 2;
  f16* Xh = (f16*)p; p += (size_t)4194304 * 2;
  uint8_t* m8 = (uint8_t*)p; p += (size_t)8388608;
  int* flag = (int*)p; p += 256;
  if (ws_size < (size_t)(p - (char*)d_ws)) return;

  mask_detect<<<1, 256, 0, stream>>>(mask, flag);
  mask_canon<<<8192, 256, 0, stream>>>(mask, m8, flag);

  cvt_f32_f16<<<4096, 256, 0, stream>>>(query, qh, 1048576);
  cvt_f32_f16<<<4096, 256, 0, stream>>>(key_, kh, 1048576);
  cvt_f32_f16<<<4096, 256, 0, stream>>>(value, vh, 1048576);
  cvt_f32_f16<<<1024, 256, 0, stream>>>(Wq, wqh, 262144);
  cvt_f32_f16<<<1024, 256, 0, stream>>>(Wk, wkh, 262144);
  cvt_f32_f16<<<1024, 256, 0, stream>>>(Wv, wvh, 262144);
  cvt_f32_f16<<<1024, 256, 0, stream>>>(Wo, woh, 262144);

  // Q pre-scaled by 1/sqrt(DK) * log2(e) so attn works in exp2 domain.
  gemm_bt<0><<<512, 256, 0, stream>>>(qh, wqh, bq, Qp, 0.125f * LOG2E);
  gemm_bt<0><<<512, 256, 0, stream>>>(kh, wkh, bk, Kp, 1.0f);
  gemm_bt<1><<<512, 256, 0, stream>>>(vh, wvh, bv, Vt, 1.0f);

  attn_fwd<<<1024, 256, 0, stream>>>(Qp, Kp, Vt, bias, m8, Xh);

  gemm_bt<2><<<512, 256, 0, stream>>>(Xh, woh, bo, d_out, 1.0f);
}

// Round 5
// 288.535 us; speedup vs baseline: 1.0773x; 1.0773x over previous
//
#include <hip/hip_runtime.h>
#include <stdint.h>

// MultiHeadedAttention: B=2,S=2048,D=1024,H=16,DK=64
// Pipeline: fused f32->f16 cvt; fused QKV proj GEMM (MFMA f16, Q pre-scaled
// by 0.125*log2e); flash attention (swapped QK^T, counted-vmcnt pipeline,
// raw s_barrier); out proj GEMM -> f32.

typedef _Float16 f16;
typedef _Float16 f16x8 __attribute__((ext_vector_type(8)));
typedef _Float16 f16x4 __attribute__((ext_vector_type(4)));
typedef float f32x4 __attribute__((ext_vector_type(4)));

#define LOG2E 1.44269504088896340736f

__device__ __forceinline__ void gload16(const void* g, void* l) {
  __builtin_amdgcn_global_load_lds(
      (const __attribute__((address_space(1))) unsigned int*)g,
      (__attribute__((address_space(3))) unsigned int*)l, 16, 0, 0);
}

// ---------------- fused f32 -> f16 conversion ------------------------------
// Destinations contiguous in ws (qh,kh,vh,wqh,wkh,wvh,woh). i indexes float4
// units: 3 inputs x 1048576 (1<<20) + 4 weights x 262144 (1<<18) = 4194304.
struct CvtSrcs { const float* s[7]; };

__global__ __launch_bounds__(256) void cvt_all(CvtSrcs a, f16* __restrict__ out) {
  const int i = blockIdx.x * 256 + threadIdx.x;  // 0 .. 4194303
  int r, base;
  if (i < 3145728) { r = i >> 20; base = r << 20; }
  else { r = 3 + ((i - 3145728) >> 18); base = 3145728 + ((r - 3) << 18); }
  const float4 v = ((const float4*)a.s[r])[i - base];
  f16x4 o = {(f16)v.x, (f16)v.y, (f16)v.z, (f16)v.w};
  ((f16x4*)out)[i] = o;
}

// ---------------- mask dtype classify + canonicalize to u8 ----------------
__global__ void mask_detect(const uint8_t* __restrict__ m, int* __restrict__ flag) {
  __shared__ int s_off, s_weird;
  const int t = threadIdx.x;
  if (t == 0) { s_off = 0; s_weird = 0; }
  __syncthreads();
  int f_off = 0, f_weird = 0;
  for (int i = t; i < 8192; i += 256) {
    const uint8_t v = m[i];
    if ((i & 3) && v) f_off = 1;
    if (v > 1) f_weird = 1;
  }
  if (f_off) atomicOr(&s_off, 1);
  if (f_weird) atomicOr(&s_weird, 1);
  __syncthreads();
  if (t == 0) *flag = (s_off && !s_weird) ? 1 : 0;  // 1 => byte-sized bool
}

__global__ __launch_bounds__(256) void mask_canon(const uint8_t* __restrict__ m,
                                                  uint8_t* __restrict__ out,
                                                  const int* __restrict__ flag) {
  const int i = (blockIdx.x * 256 + threadIdx.x) * 4;  // grid covers 8388608
  uchar4 o;
  if (*flag) {
    const uchar4 v = *(const uchar4*)(m + i);
    o = make_uchar4(v.x != 0, v.y != 0, v.z != 0, v.w != 0);
  } else {
    const int4 v = *(const int4*)((const int*)m + i);
    o = make_uchar4(v.x != 0, v.y != 0, v.z != 0, v.w != 0);
  }
  *(uchar4*)(out + i) = o;
}

// ---------------- fused QKV projection GEMM --------------------------------
// grid 1536: bid -> (mt = bid/48, nt = bid%48). which = nt>>4 picks Q/K/V.
// C[m,n] = (sum_k A[m,k]*W[n,k] + bias[n]) * scale. Q scaled by 0.125*log2e.
// Q,K written [B,H,S,DK]; V written transposed [B,H,DK,S].
__global__ __launch_bounds__(256, 2) void gemm_qkv(
    const f16* __restrict__ qh, const f16* __restrict__ kh, const f16* __restrict__ vh,
    const f16* __restrict__ wq, const f16* __restrict__ wk, const f16* __restrict__ wv,
    const float* __restrict__ bq, const float* __restrict__ bk, const float* __restrict__ bv,
    f16* __restrict__ Qp, f16* __restrict__ Kp, f16* __restrict__ Vt) {
  constexpr int K = 1024;
  const int t = threadIdx.x;
  const int w = t >> 6, lane = t & 63, l15 = lane & 15, l4 = lane >> 4;
  const int nt = (int)blockIdx.x % 48;
  const int bm = ((int)blockIdx.x / 48) * 128;
  const int which = nt >> 4;
  const int bn = (nt & 15) * 64;
  const f16* A = which == 0 ? qh : which == 1 ? kh : vh;
  const f16* Bw = which == 0 ? wq : which == 1 ? wk : wv;
  const float* bias = which == 0 ? bq : which == 1 ? bk : bv;

  __shared__ f16 As[2][128 * 32];
  __shared__ f16 Bs[2][64 * 32];

  const f16* a0 = A + (size_t)(bm + (t >> 2)) * K + (t & 3) * 8;
  const f16* a1 = a0 + (size_t)64 * K;
  const f16* b0 = Bw + (size_t)(bn + (t >> 2)) * K + (t & 3) * 8;

  f32x4 acc[2][4];
#pragma unroll
  for (int m = 0; m < 2; ++m)
#pragma unroll
    for (int n = 0; n < 4; ++n) acc[m][n] = (f32x4){0.f, 0.f, 0.f, 0.f};

#define STAGE_G(buf, k0)                          \
  do {                                            \
    gload16(a0 + (k0), &As[buf][w * 512]);        \
    gload16(a1 + (k0), &As[buf][2048 + w * 512]); \
    gload16(b0 + (k0), &Bs[buf][w * 512]);        \
  } while (0)

  STAGE_G(0, 0);
  __syncthreads();
  int cur = 0;
#pragma unroll 1
  for (int kt = 0; kt < 32; ++kt) {
    if (kt < 31) STAGE_G(cur ^ 1, (kt + 1) * 32);
    const f16* ap = &As[cur][(w * 32 + l15) * 32 + l4 * 8];
    const f16* bp = &Bs[cur][l15 * 32 + l4 * 8];
    f16x8 af[2], bfr[4];
#pragma unroll
    for (int m = 0; m < 2; ++m) af[m] = *(const f16x8*)(ap + m * 512);
#pragma unroll
    for (int n = 0; n < 4; ++n) bfr[n] = *(const f16x8*)(bp + n * 512);
#pragma unroll
    for (int m = 0; m < 2; ++m)
#pragma unroll
      for (int n = 0; n < 4; ++n)
        acc[m][n] = __builtin_amdgcn_mfma_f32_16x16x32_f16(af[m], bfr[n], acc[m][n], 0, 0, 0);
    __syncthreads();
    cur ^= 1;
  }
#undef STAGE_G

  const float scale = which == 0 ? 0.125f * LOG2E : 1.0f;
  f16* outp = which == 0 ? Qp : which == 1 ? Kp : Vt;
#pragma unroll
  for (int m = 0; m < 2; ++m) {
    const int r0 = bm + w * 32 + m * 16 + (l4 << 2);
#pragma unroll
    for (int n = 0; n < 4; ++n) {
      const int c = bn + n * 16 + l15;
      const float bv = bias[c];
#pragma unroll
      for (int j = 0; j < 4; ++j) {
        const int r = r0 + j;
        const float v = (acc[m][n][j] + bv) * scale;
        const int b_ = r >> 11, s = r & 2047, h_ = c >> 6, dk = c & 63;
        if (which < 2)
          outp[(((size_t)b_ * 16 + h_) * 2048 + s) * 64 + dk] = (f16)v;
        else
          outp[(((size_t)b_ * 16 + h_) * 64 + dk) * 2048 + s] = (f16)v;
      }
    }
  }
}

// ---------------- output projection GEMM (f32 out) -------------------------
__global__ __launch_bounds__(256, 2) void gemm_out(const f16* __restrict__ A,
                                                   const f16* __restrict__ Bw,
                                                   const float* __restrict__ bias,
                                                   float* __restrict__ outp) {
  constexpr int K = 1024;
  const int t = threadIdx.x;
  const int w = t >> 6, lane = t & 63, l15 = lane & 15, l4 = lane >> 4;
  const int bm = (int)(blockIdx.x >> 4) * 128;
  const int bn = (int)(blockIdx.x & 15) * 64;

  __shared__ f16 As[2][128 * 32];
  __shared__ f16 Bs[2][64 * 32];

  const f16* a0 = A + (size_t)(bm + (t >> 2)) * K + (t & 3) * 8;
  const f16* a1 = a0 + (size_t)64 * K;
  const f16* b0 = Bw + (size_t)(bn + (t >> 2)) * K + (t & 3) * 8;

  f32x4 acc[2][4];
#pragma unroll
  for (int m = 0; m < 2; ++m)
#pragma unroll
    for (int n = 0; n < 4; ++n) acc[m][n] = (f32x4){0.f, 0.f, 0.f, 0.f};

#define STAGE_G(buf, k0)                          \
  do {                                            \
    gload16(a0 + (k0), &As[buf][w * 512]);        \
    gload16(a1 + (k0), &As[buf][2048 + w * 512]); \
    gload16(b0 + (k0), &Bs[buf][w * 512]);        \
  } while (0)

  STAGE_G(0, 0);
  __syncthreads();
  int cur = 0;
#pragma unroll 1
  for (int kt = 0; kt < 32; ++kt) {
    if (kt < 31) STAGE_G(cur ^ 1, (kt + 1) * 32);
    const f16* ap = &As[cur][(w * 32 + l15) * 32 + l4 * 8];
    const f16* bp = &Bs[cur][l15 * 32 + l4 * 8];
    f16x8 af[2], bfr[4];
#pragma unroll
    for (int m = 0; m < 2; ++m) af[m] = *(const f16x8*)(ap + m * 512);
#pragma unroll
    for (int n = 0; n < 4; ++n) bfr[n] = *(const f16x8*)(bp + n * 512);
#pragma unroll
    for (int m = 0; m < 2; ++m)
#pragma unroll
      for (int n = 0; n < 4; ++n)
        acc[m][n] = __builtin_amdgcn_mfma_f32_16x16x32_f16(af[m], bfr[n], acc[m][n], 0, 0, 0);
    __syncthreads();
    cur ^= 1;
  }
#undef STAGE_G

#pragma unroll
  for (int m = 0; m < 2; ++m) {
    const int r0 = bm + w * 32 + m * 16 + (l4 << 2);
#pragma unroll
    for (int n = 0; n < 4; ++n) {
      const int c = bn + n * 16 + l15;
      const float bv = bias[c];
#pragma unroll
      for (int j = 0; j < 4; ++j)
        outp[(size_t)(r0 + j) * 1024 + c] = acc[m][n][j] + bv;
    }
  }
}

// ---------------- flash attention (swapped QK^T, counted-vmcnt pipeline) ---
// 1024 blocks: bid -> (qt 0..31, b, h). 4 waves x 16 q-rows, kv tile 64.
// K/V double-buffered; raw s_barrier + asm vmcnt(4): tile kt+1's 4 gload_lds
// stay in flight across the barrier (never drain to 0 in the loop). STAGE of
// tile kt+2 goes after a second (non-draining) barrier -> one full tile of
// flight time per staging. Bias/mask loads issue right after the top barrier
// and are covered by the QK^T window.
__device__ __forceinline__ const f16x8* swzr(const f16* base, int row, int bytecol) {
  return (const f16x8*)((const char*)base + row * 128 + (bytecol ^ ((row & 7) << 4)));
}

__global__ __launch_bounds__(256, 4) void attn_fwd(
    const f16* __restrict__ Qp, const f16* __restrict__ Kp,
    const f16* __restrict__ Vt, const float* __restrict__ bias,
    const uint8_t* __restrict__ mask, f16* __restrict__ X) {
  constexpr int S = 2048;
  const int bid = blockIdx.x;
  const int qt = bid & 31, b = (bid >> 5) & 1, h = bid >> 6;
  const int t = threadIdx.x, w = t >> 6, lane = t & 63;
  const int l15 = lane & 15, l4 = lane >> 4;
  const int q0 = qt * 64 + w * 16;

  const f16* Qbh = Qp + (size_t)(b * 16 + h) * S * 64;
  const f16* Kbh = Kp + (size_t)(b * 16 + h) * S * 64;
  const f16* Vbh = Vt + (size_t)(b * 16 + h) * 64 * S;
  const float* biasr = bias + (size_t)h * S * S + (size_t)(q0 + l15) * S + l4 * 4;
  const uint8_t* maskr = mask + (size_t)b * S * S + (size_t)(q0 + l15) * S + l4 * 4;

  __shared__ f16 Ks[2][64 * 64];  // [kv][dk], swizzled
  __shared__ f16 Vs[2][64 * 64];  // [dk][kv], swizzled
  __shared__ f16 Ps[4][16 * 64];  // per-wave P [q][k], swizzled

  // Q B-frag: row = q = l15, k = ks*32 + l4*8 + i (Q pre-scaled by 0.125*log2e)
  f16x8 qf[2];
#pragma unroll
  for (int ks = 0; ks < 2; ++ks)
    qf[ks] = *(const f16x8*)(Qbh + (size_t)(q0 + l15) * 64 + ks * 32 + l4 * 8);

  f32x4 oacc[4];  // O[q = q0+l4*4+j, d = n*16+l15]
#pragma unroll
  for (int n = 0; n < 4; ++n) oacc[n] = (f32x4){0.f, 0.f, 0.f, 0.f};
  float mrow = -3e38f, lrow = 0.f;  // stats for q = q0 + l15

  const int srow = t >> 3;
  const int scol = (((t & 7) ^ (srow & 7)) << 3);

#define STAGE(bf, kk)                                                               \
  do {                                                                              \
    gload16(Kbh + (size_t)((kk) + srow) * 64 + scol, &Ks[bf][w * 512]);             \
    gload16(Kbh + (size_t)((kk) + 32 + srow) * 64 + scol, &Ks[bf][2048 + w * 512]); \
    gload16(Vbh + (size_t)srow * S + (kk) + scol, &Vs[bf][w * 512]);                \
    gload16(Vbh + (size_t)(32 + srow) * S + (kk) + scol, &Vs[bf][2048 + w * 512]);  \
  } while (0)

  STAGE(0, 0);
  STAGE(1, 64);

#pragma unroll 1
  for (int kt = 0; kt < 32; ++kt) {
    const int k0 = kt * 64;
    const int buf = kt & 1;
    // tile kt ready (its 4 gload_lds are older than the newest 4 = tile kt+1)
    asm volatile("s_waitcnt vmcnt(4)" ::: "memory");
    __builtin_amdgcn_s_barrier();  // all waves' tile-kt staging visible

    // bias/mask loads for this tile — overlapped with QK^T below
    f32x4 bc[4];
    uint32_t mc[4];
#pragma unroll
    for (int n = 0; n < 4; ++n) {
      bc[n] = *(const f32x4*)(biasr + k0 + n * 16);
      mc[n] = *(const uint32_t*)(maskr + k0 + n * 16);
    }

    // ---- scores (swapped): sacc[n][j] = s(q=q0+l15, k=k0+16n+4*l4+j) ----
    f32x4 sacc[4];
#pragma unroll
    for (int n = 0; n < 4; ++n) sacc[n] = (f32x4){0.f, 0.f, 0.f, 0.f};
#pragma unroll
    for (int n = 0; n < 4; ++n)
#pragma unroll
      for (int ks = 0; ks < 2; ++ks) {
        const f16x8 kf = *swzr(&Ks[buf][0], n * 16 + l15, ks * 64 + l4 * 16);
        sacc[n] = __builtin_amdgcn_mfma_f32_16x16x32_f16(kf, qf[ks], sacc[n], 0, 0, 0);
      }

    // ---- bias + mask (log2e domain), in-register row max ----
    float tmax = -3e38f;
#pragma unroll
    for (int n = 0; n < 4; ++n)
#pragma unroll
      for (int j = 0; j < 4; ++j) {
        float s = fmaf(bc[n][j], LOG2E, sacc[n][j]);
        s = ((mc[n] >> (8 * j)) & 255u) ? -1.44269504e9f : s;
        sacc[n][j] = s;
        tmax = fmaxf(tmax, s);
      }
    tmax = fmaxf(tmax, __shfl_xor(tmax, 16));
    tmax = fmaxf(tmax, __shfl_xor(tmax, 32));

    // ---- online softmax (per-lane scalars) ----
    const float mnew = fmaxf(mrow, tmax);
    const float alpha = __builtin_exp2f(mrow - mnew);
    mrow = mnew;
    float lsum = 0.f;
#pragma unroll
    for (int n = 0; n < 4; ++n)
#pragma unroll
      for (int j = 0; j < 4; ++j) {
        const float e = __builtin_exp2f(sacc[n][j] - mnew);
        sacc[n][j] = e;
        lsum += e;
      }
    lsum += __shfl_xor(lsum, 16);
    lsum += __shfl_xor(lsum, 32);
    lrow = lrow * alpha + lsum;

    // ---- rescale O by alpha of its q-row ----
    float aq[4];
#pragma unroll
    for (int j = 0; j < 4; ++j) aq[j] = __shfl(alpha, l4 * 4 + j);
#pragma unroll
    for (int n = 0; n < 4; ++n)
#pragma unroll
      for (int j = 0; j < 4; ++j) oacc[n][j] *= aq[j];

    // ---- P -> per-wave LDS (packed f16x4, swizzled) ----
#pragma unroll
    for (int n = 0; n < 4; ++n) {
      f16x4 pk = {(f16)sacc[n][0], (f16)sacc[n][1], (f16)sacc[n][2], (f16)sacc[n][3]};
      *(f16x4*)((char*)&Ps[w][0] + l15 * 128 +
                ((32 * n + 8 * l4) ^ ((l15 & 7) << 4))) = pk;
    }

    // ---- O += P.V ----
    f16x8 pf[2];
#pragma unroll
    for (int ks = 0; ks < 2; ++ks) pf[ks] = *swzr(&Ps[w][0], l15, ks * 64 + l4 * 16);
#pragma unroll
    for (int ks = 0; ks < 2; ++ks)
#pragma unroll
      for (int n = 0; n < 4; ++n) {
        const f16x8 vf = *swzr(&Vs[buf][0], n * 16 + l15, ks * 64 + l4 * 16);
        oacc[n] = __builtin_amdgcn_mfma_f32_16x16x32_f16(pf[ks], vf, oacc[n], 0, 0, 0);
      }

    // all waves done reading buf (reads architecturally complete pre-barrier)
    __builtin_amdgcn_s_barrier();
    // stage tile kt+2 into the buffer just freed; (…)&2047 keeps the vmcnt
    // count uniform on the last two iters (dummy re-stage, never read)
    STAGE(buf, (k0 + 128) & (S - 1));
  }
#undef STAGE

  // drain outstanding dummy stages before LDS dealloc / kernel end
  asm volatile("s_waitcnt vmcnt(0)" ::: "memory");

  // ---- normalize and store X[b,s,h*64+d] (f16) ----
  const float inv = 1.0f / lrow;
  float invq[4];
#pragma unroll
  for (int j = 0; j < 4; ++j) invq[j] = __shfl(inv, l4 * 4 + j);
#pragma unroll
  for (int j = 0; j < 4; ++j) {
    const int qrow = q0 + l4 * 4 + j;
#pragma unroll
    for (int n = 0; n < 4; ++n)
      X[((size_t)b * 2048 + qrow) * 1024 + h * 64 + n * 16 + l15] =
          (f16)(oacc[n][j] * invq[j]);
  }
}

// ---------------- host ------------------------------------------------------
extern "C" void kernel_launch(void* const* d_in, const int* in_sizes, int n_in,
                              void* d_out, int out_size, void* d_ws, size_t ws_size,
                              hipStream_t stream) {
  const float* query = (const float*)d_in[0];
  const float* key_ = (const float*)d_in[1];
  const float* value = (const float*)d_in[2];
  const uint8_t* mask = (const uint8_t*)d_in[3];
  const float* bias = (const float*)d_in[4];
  const float* Wq = (const float*)d_in[5];
  const float* bq = (const float*)d_in[6];
  const float* Wk = (const float*)d_in[7];
  const float* bk = (const float*)d_in[8];
  const float* Wv = (const float*)d_in[9];
  const float* bv = (const float*)d_in[10];
  const float* Wo = (const float*)d_in[11];
  const float* bo = (const float*)d_in[12];

  char* p = (char*)d_ws;
  f16* qh = (f16*)p; p += (size_t)4194304 * 2;   // contiguous cvt dst region:
  f16* kh = (f16*)p; p += (size_t)4194304 * 2;   // qh,kh,vh,wqh,wkh,wvh,woh
  f16* vh = (f16*)p; p += (size_t)4194304 * 2;
  f16* wqh = (f16*)p; p += (size_t)1048576 * 2;
  f16* wkh = (f16*)p; p += (size_t)1048576 * 2;
  f16* wvh = (f16*)p; p += (size_t)1048576 * 2;
  f16* woh = (f16*)p; p += (size_t)1048576 * 2;
  f16* Qp = (f16*)p; p += (size_t)4194304 * 2;
  f16* Kp = (f16*)p; p += (size_t)4194304 * 2;
  f16* Vt = (f16*)p; p += (size_t)4194304 * 2;
  f16* Xh = (f16*)p; p += (size_t)4194304 * 2;
  uint8_t* m8 = (uint8_t*)p; p += (size_t)8388608;
  int* flag = (int*)p; p += 256;
  if (ws_size < (size_t)(p - (char*)d_ws)) return;

  mask_detect<<<1, 256, 0, stream>>>(mask, flag);
  mask_canon<<<8192, 256, 0, stream>>>(mask, m8, flag);

  CvtSrcs cs;
  cs.s[0] = query; cs.s[1] = key_; cs.s[2] = value;
  cs.s[3] = Wq; cs.s[4] = Wk; cs.s[5] = Wv; cs.s[6] = Wo;
  cvt_all<<<16384, 256, 0, stream>>>(cs, qh);

  gemm_qkv<<<1536, 256, 0, stream>>>(qh, kh, vh, wqh, wkh, wvh, bq, bk, bv,
                                     Qp, Kp, Vt);

  attn_fwd<<<1024, 256, 0, stream>>>(Qp, Kp, Vt, bias, m8, Xh);

  gemm_out<<<512, 256, 0, stream>>>(Xh, woh, bo, (float*)d_out);
}

// Round 7
// 256.569 us; speedup vs baseline: 1.2115x; 1.1246x over previous
//
#include <hip/hip_runtime.h>
#include <stdint.h>

// MultiHeadedAttention: B=2,S=2048,D=1024,H=16,DK=64
// Pipeline: fused f32->f16 cvt; fused QKV proj GEMM (MFMA f16, Q pre-scaled
// by 0.125*log2e); batch-merged flash attention (one block does b=0 AND b=1
// for a (h,q-tile): bias loaded once, reused for both batches); out proj.

typedef _Float16 f16;
typedef _Float16 f16x8 __attribute__((ext_vector_type(8)));
typedef _Float16 f16x4 __attribute__((ext_vector_type(4)));
typedef __fp16 h2 __attribute__((ext_vector_type(2)));
typedef float f32x4 __attribute__((ext_vector_type(4)));

#define LOG2E 1.44269504088896340736f

__device__ __forceinline__ void gload16(const void* g, void* l) {
  __builtin_amdgcn_global_load_lds(
      (const __attribute__((address_space(1))) unsigned int*)g,
      (__attribute__((address_space(3))) unsigned int*)l, 16, 0, 0);
}

// ---------------- fused f32 -> f16 conversion ------------------------------
// Destinations contiguous in ws (qh,kh,vh,wqh,wkh,wvh,woh). i indexes float4
// units: 3 inputs x 1048576 (1<<20) + 4 weights x 262144 (1<<18) = 4194304.
struct CvtSrcs { const float* s[7]; };

__global__ __launch_bounds__(256) void cvt_all(CvtSrcs a, f16* __restrict__ out) {
  const int i = blockIdx.x * 256 + threadIdx.x;  // 0 .. 4194303
  int r, base;
  if (i < 3145728) { r = i >> 20; base = r << 20; }
  else { r = 3 + ((i - 3145728) >> 18); base = 3145728 + ((r - 3) << 18); }
  const float4 v = ((const float4*)a.s[r])[i - base];
  f16x4 o = {(f16)v.x, (f16)v.y, (f16)v.z, (f16)v.w};
  ((f16x4*)out)[i] = o;
}

// ---------------- mask dtype classify + canonicalize to u8 ----------------
__global__ void mask_detect(const uint8_t* __restrict__ m, int* __restrict__ flag) {
  __shared__ int s_off, s_weird;
  const int t = threadIdx.x;
  if (t == 0) { s_off = 0; s_weird = 0; }
  __syncthreads();
  int f_off = 0, f_weird = 0;
  for (int i = t; i < 8192; i += 256) {
    const uint8_t v = m[i];
    if ((i & 3) && v) f_off = 1;
    if (v > 1) f_weird = 1;
  }
  if (f_off) atomicOr(&s_off, 1);
  if (f_weird) atomicOr(&s_weird, 1);
  __syncthreads();
  if (t == 0) *flag = (s_off && !s_weird) ? 1 : 0;  // 1 => byte-sized bool
}

__global__ __launch_bounds__(256) void mask_canon(const uint8_t* __restrict__ m,
                                                  uint8_t* __restrict__ out,
                                                  const int* __restrict__ flag) {
  const int i = (blockIdx.x * 256 + threadIdx.x) * 4;  // grid covers 8388608
  uchar4 o;
  if (*flag) {
    const uchar4 v = *(const uchar4*)(m + i);
    o = make_uchar4(v.x != 0, v.y != 0, v.z != 0, v.w != 0);
  } else {
    const int4 v = *(const int4*)((const int*)m + i);
    o = make_uchar4(v.x != 0, v.y != 0, v.z != 0, v.w != 0);
  }
  *(uchar4*)(out + i) = o;
}

// ---------------- fused QKV projection GEMM --------------------------------
__global__ __launch_bounds__(256, 2) void gemm_qkv(
    const f16* __restrict__ qh, const f16* __restrict__ kh, const f16* __restrict__ vh,
    const f16* __restrict__ wq, const f16* __restrict__ wk, const f16* __restrict__ wv,
    const float* __restrict__ bq, const float* __restrict__ bk, const float* __restrict__ bv,
    f16* __restrict__ Qp, f16* __restrict__ Kp, f16* __restrict__ Vt) {
  constexpr int K = 1024;
  const int t = threadIdx.x;
  const int w = t >> 6, lane = t & 63, l15 = lane & 15, l4 = lane >> 4;
  const int nt = (int)blockIdx.x % 48;
  const int bm = ((int)blockIdx.x / 48) * 128;
  const int which = nt >> 4;
  const int bn = (nt & 15) * 64;
  const f16* A = which == 0 ? qh : which == 1 ? kh : vh;
  const f16* Bw = which == 0 ? wq : which == 1 ? wk : wv;
  const float* bias = which == 0 ? bq : which == 1 ? bk : bv;

  __shared__ f16 As[2][128 * 32];
  __shared__ f16 Bs[2][64 * 32];

  const f16* a0 = A + (size_t)(bm + (t >> 2)) * K + (t & 3) * 8;
  const f16* a1 = a0 + (size_t)64 * K;
  const f16* b0 = Bw + (size_t)(bn + (t >> 2)) * K + (t & 3) * 8;

  f32x4 acc[2][4];
#pragma unroll
  for (int m = 0; m < 2; ++m)
#pragma unroll
    for (int n = 0; n < 4; ++n) acc[m][n] = (f32x4){0.f, 0.f, 0.f, 0.f};

#define STAGE_G(buf, k0)                          \
  do {                                            \
    gload16(a0 + (k0), &As[buf][w * 512]);        \
    gload16(a1 + (k0), &As[buf][2048 + w * 512]); \
    gload16(b0 + (k0), &Bs[buf][w * 512]);        \
  } while (0)

  STAGE_G(0, 0);
  __syncthreads();
  int cur = 0;
#pragma unroll 1
  for (int kt = 0; kt < 32; ++kt) {
    if (kt < 31) STAGE_G(cur ^ 1, (kt + 1) * 32);
    const f16* ap = &As[cur][(w * 32 + l15) * 32 + l4 * 8];
    const f16* bp = &Bs[cur][l15 * 32 + l4 * 8];
    f16x8 af[2], bfr[4];
#pragma unroll
    for (int m = 0; m < 2; ++m) af[m] = *(const f16x8*)(ap + m * 512);
#pragma unroll
    for (int n = 0; n < 4; ++n) bfr[n] = *(const f16x8*)(bp + n * 512);
#pragma unroll
    for (int m = 0; m < 2; ++m)
#pragma unroll
      for (int n = 0; n < 4; ++n)
        acc[m][n] = __builtin_amdgcn_mfma_f32_16x16x32_f16(af[m], bfr[n], acc[m][n], 0, 0, 0);
    __syncthreads();
    cur ^= 1;
  }
#undef STAGE_G

  const float scale = which == 0 ? 0.125f * LOG2E : 1.0f;
  f16* outp = which == 0 ? Qp : which == 1 ? Kp : Vt;
#pragma unroll
  for (int m = 0; m < 2; ++m) {
    const int r0 = bm + w * 32 + m * 16 + (l4 << 2);
#pragma unroll
    for (int n = 0; n < 4; ++n) {
      const int c = bn + n * 16 + l15;
      const float bv = bias[c];
#pragma unroll
      for (int j = 0; j < 4; ++j) {
        const int r = r0 + j;
        const float v = (acc[m][n][j] + bv) * scale;
        const int b_ = r >> 11, s = r & 2047, h_ = c >> 6, dk = c & 63;
        if (which < 2)
          outp[(((size_t)b_ * 16 + h_) * 2048 + s) * 64 + dk] = (f16)v;
        else
          outp[(((size_t)b_ * 16 + h_) * 64 + dk) * 2048 + s] = (f16)v;
      }
    }
  }
}

// ---------------- output projection GEMM (f32 out) -------------------------
__global__ __launch_bounds__(256, 2) void gemm_out(const f16* __restrict__ A,
                                                   const f16* __restrict__ Bw,
                                                   const float* __restrict__ bias,
                                                   float* __restrict__ outp) {
  constexpr int K = 1024;
  const int t = threadIdx.x;
  const int w = t >> 6, lane = t & 63, l15 = lane & 15, l4 = lane >> 4;
  const int bm = (int)(blockIdx.x >> 4) * 128;
  const int bn = (int)(blockIdx.x & 15) * 64;

  __shared__ f16 As[2][128 * 32];
  __shared__ f16 Bs[2][64 * 32];

  const f16* a0 = A + (size_t)(bm + (t >> 2)) * K + (t & 3) * 8;
  const f16* a1 = a0 + (size_t)64 * K;
  const f16* b0 = Bw + (size_t)(bn + (t >> 2)) * K + (t & 3) * 8;

  f32x4 acc[2][4];
#pragma unroll
  for (int m = 0; m < 2; ++m)
#pragma unroll
    for (int n = 0; n < 4; ++n) acc[m][n] = (f32x4){0.f, 0.f, 0.f, 0.f};

#define STAGE_G(buf, k0)                          \
  do {                                            \
    gload16(a0 + (k0), &As[buf][w * 512]);        \
    gload16(a1 + (k0), &As[buf][2048 + w * 512]); \
    gload16(b0 + (k0), &Bs[buf][w * 512]);        \
  } while (0)

  STAGE_G(0, 0);
  __syncthreads();
  int cur = 0;
#pragma unroll 1
  for (int kt = 0; kt < 32; ++kt) {
    if (kt < 31) STAGE_G(cur ^ 1, (kt + 1) * 32);
    const f16* ap = &As[cur][(w * 32 + l15) * 32 + l4 * 8];
    const f16* bp = &Bs[cur][l15 * 32 + l4 * 8];
    f16x8 af[2], bfr[4];
#pragma unroll
    for (int m = 0; m < 2; ++m) af[m] = *(const f16x8*)(ap + m * 512);
#pragma unroll
    for (int n = 0; n < 4; ++n) bfr[n] = *(const f16x8*)(bp + n * 512);
#pragma unroll
    for (int m = 0; m < 2; ++m)
#pragma unroll
      for (int n = 0; n < 4; ++n)
        acc[m][n] = __builtin_amdgcn_mfma_f32_16x16x32_f16(af[m], bfr[n], acc[m][n], 0, 0, 0);
    __syncthreads();
    cur ^= 1;
  }
#undef STAGE_G

#pragma unroll
  for (int m = 0; m < 2; ++m) {
    const int r0 = bm + w * 32 + m * 16 + (l4 << 2);
#pragma unroll
    for (int n = 0; n < 4; ++n) {
      const int c = bn + n * 16 + l15;
      const float bv = bias[c];
#pragma unroll
      for (int j = 0; j < 4; ++j)
        outp[(size_t)(r0 + j) * 1024 + c] = acc[m][n][j] + bv;
    }
  }
}

// ---------------- batch-merged flash attention -----------------------------
// 512 blocks: bid -> (qt 0..31, h 0..15). Each block computes BOTH batches
// for its (h, 64-q-row tile): bias (batch-independent) loaded once per tile
// and reused; K/V for both batches staged in LDS (single-buffered); b0/b1
// chains are independent -> per-wave ILP doubles. Mask folded in via
// byte-extract + fmaf(-2e9) (clang lowers to v_cvt_f32_ubyte).
__device__ __forceinline__ const f16x8* swzr(const f16* base, int row, int bytecol) {
  return (const f16x8*)((const char*)base + row * 128 + (bytecol ^ ((row & 7) << 4)));
}

__global__ __launch_bounds__(256, 2) void attn_fwd(
    const f16* __restrict__ Qp, const f16* __restrict__ Kp,
    const f16* __restrict__ Vt, const float* __restrict__ bias,
    const uint8_t* __restrict__ mask, f16* __restrict__ X) {
  constexpr int S = 2048;
  const int bid = blockIdx.x;
  const int qt = bid & 31, h = bid >> 5;
  const int t = threadIdx.x, w = t >> 6, lane = t & 63;
  const int l15 = lane & 15, l4 = lane >> 4;
  const int q0 = qt * 64 + w * 16;

  const f16* Qb[2] = {Qp + (size_t)h * S * 64, Qp + (size_t)(16 + h) * S * 64};
  const f16* Kb[2] = {Kp + (size_t)h * S * 64, Kp + (size_t)(16 + h) * S * 64};
  const f16* Vb[2] = {Vt + (size_t)h * 64 * S, Vt + (size_t)(16 + h) * 64 * S};
  const float* biasr = bias + (size_t)h * S * S + (size_t)(q0 + l15) * S + l4 * 4;
  const uint8_t* mr0 = mask + (size_t)(q0 + l15) * S + l4 * 4;
  const uint8_t* mr1 = mr0 + (size_t)S * S;

  __shared__ f16 Ks[2][64 * 64];  // [batch][kv][dk], swizzled
  __shared__ f16 Vs[2][64 * 64];  // [batch][dk][kv], swizzled
  __shared__ f16 Ps[4][16 * 64];  // per-wave P, swizzled (reused b0 then b1)

  // Q B-frags for both batches (Q pre-scaled by 0.125*log2e)
  f16x8 qf[2][2];
#pragma unroll
  for (int bb = 0; bb < 2; ++bb)
#pragma unroll
    for (int ks = 0; ks < 2; ++ks)
      qf[bb][ks] =
          *(const f16x8*)(Qb[bb] + (size_t)(q0 + l15) * 64 + ks * 32 + l4 * 8);

  f32x4 oacc[2][4];
#pragma unroll
  for (int bb = 0; bb < 2; ++bb)
#pragma unroll
    for (int n = 0; n < 4; ++n) oacc[bb][n] = (f32x4){0.f, 0.f, 0.f, 0.f};
  float mrow[2] = {-3e38f, -3e38f}, lrow[2] = {0.f, 0.f};

  const int srow = t >> 3;
  const int scol = (((t & 7) ^ (srow & 7)) << 3);

#define STAGE(kk)                                                                   \
  do {                                                                              \
    gload16(Kb[0] + (size_t)((kk) + srow) * 64 + scol, &Ks[0][w * 512]);            \
    gload16(Kb[0] + (size_t)((kk) + 32 + srow) * 64 + scol, &Ks[0][2048 + w * 512]);\
    gload16(Kb[1] + (size_t)((kk) + srow) * 64 + scol, &Ks[1][w * 512]);            \
    gload16(Kb[1] + (size_t)((kk) + 32 + srow) * 64 + scol, &Ks[1][2048 + w * 512]);\
    gload16(Vb[0] + (size_t)srow * S + (kk) + scol, &Vs[0][w * 512]);               \
    gload16(Vb[0] + (size_t)(32 + srow) * S + (kk) + scol, &Vs[0][2048 + w * 512]); \
    gload16(Vb[1] + (size_t)srow * S + (kk) + scol, &Vs[1][w * 512]);               \
    gload16(Vb[1] + (size_t)(32 + srow) * S + (kk) + scol, &Vs[1][2048 + w * 512]); \
  } while (0)

  STAGE(0);

#pragma unroll 1
  for (int kt = 0; kt < 32; ++kt) {
    const int k0 = kt * 64;
    // bias (shared by both batches) + masks — issued pre-barrier, drained by it
    f32x4 bc[4];
    uint32_t mc[2][4];
#pragma unroll
    for (int n = 0; n < 4; ++n) {
      bc[n] = *(const f32x4*)(biasr + k0 + n * 16);
      mc[0][n] = *(const uint32_t*)(mr0 + k0 + n * 16);
      mc[1][n] = *(const uint32_t*)(mr1 + k0 + n * 16);
    }
    __syncthreads();  // drains vmcnt: K/V tiles + bias/mask regs ready

    // ---- QK^T for both batches (swapped: lane owns q=q0+l15) ----
    f32x4 sacc[2][4];
#pragma unroll
    for (int bb = 0; bb < 2; ++bb)
#pragma unroll
      for (int n = 0; n < 4; ++n) sacc[bb][n] = (f32x4){0.f, 0.f, 0.f, 0.f};
#pragma unroll
    for (int bb = 0; bb < 2; ++bb)
#pragma unroll
      for (int n = 0; n < 4; ++n)
#pragma unroll
        for (int ks = 0; ks < 2; ++ks) {
          const f16x8 kf = *swzr(&Ks[bb][0], n * 16 + l15, ks * 64 + l4 * 16);
          sacc[bb][n] =
              __builtin_amdgcn_mfma_f32_16x16x32_f16(kf, qf[bb][ks], sacc[bb][n], 0, 0, 0);
        }

    // ---- per-batch softmax + PV (Ps reused sequentially) ----
#pragma unroll
    for (int bb = 0; bb < 2; ++bb) {
      float tmax = -3e38f;
#pragma unroll
      for (int n = 0; n < 4; ++n) {
#pragma unroll
        for (int j = 0; j < 4; ++j) {
          const float mf = (float)((mc[bb][n] >> (8 * j)) & 255u);
          sacc[bb][n][j] = fmaf(mf, -2e9f, fmaf(bc[n][j], LOG2E, sacc[bb][n][j]));
        }
        tmax = fmaxf(tmax, fmaxf(fmaxf(sacc[bb][n][0], sacc[bb][n][1]),
                                 fmaxf(sacc[bb][n][2], sacc[bb][n][3])));
      }
      tmax = fmaxf(tmax, __shfl_xor(tmax, 16));
      tmax = fmaxf(tmax, __shfl_xor(tmax, 32));

      const float mnew = fmaxf(mrow[bb], tmax);
      const float alpha = __builtin_exp2f(mrow[bb] - mnew);
      mrow[bb] = mnew;
      float lsum = 0.f;
#pragma unroll
      for (int n = 0; n < 4; ++n)
#pragma unroll
        for (int j = 0; j < 4; ++j) {
          const float e = __builtin_exp2f(sacc[bb][n][j] - mnew);
          sacc[bb][n][j] = e;
          lsum += e;
        }
      lsum += __shfl_xor(lsum, 16);
      lsum += __shfl_xor(lsum, 32);
      lrow[bb] = lrow[bb] * alpha + lsum;

      float aq[4];
#pragma unroll
      for (int j = 0; j < 4; ++j) aq[j] = __shfl(alpha, l4 * 4 + j);
#pragma unroll
      for (int n = 0; n < 4; ++n)
#pragma unroll
        for (int j = 0; j < 4; ++j) oacc[bb][n][j] *= aq[j];

      // P -> per-wave LDS (pkrtz pairs, 8B swizzled writes)
#pragma unroll
      for (int n = 0; n < 4; ++n) {
        h2 p01 = __builtin_amdgcn_cvt_pkrtz(sacc[bb][n][0], sacc[bb][n][1]);
        h2 p23 = __builtin_amdgcn_cvt_pkrtz(sacc[bb][n][2], sacc[bb][n][3]);
        f16x4 pk;
        pk[0] = (f16)p01[0]; pk[1] = (f16)p01[1];
        pk[2] = (f16)p23[0]; pk[3] = (f16)p23[1];
        *(f16x4*)((char*)&Ps[w][0] + l15 * 128 +
                  ((32 * n + 8 * l4) ^ ((l15 & 7) << 4))) = pk;
      }

      // O += P.V
      f16x8 pf[2];
#pragma unroll
      for (int ks = 0; ks < 2; ++ks)
        pf[ks] = *swzr(&Ps[w][0], l15, ks * 64 + l4 * 16);
#pragma unroll
      for (int ks = 0; ks < 2; ++ks)
#pragma unroll
        for (int n = 0; n < 4; ++n) {
          const f16x8 vf = *swzr(&Vs[bb][0], n * 16 + l15, ks * 64 + l4 * 16);
          oacc[bb][n] =
              __builtin_amdgcn_mfma_f32_16x16x32_f16(pf[ks], vf, oacc[bb][n], 0, 0, 0);
        }
    }

    __syncthreads();  // all waves done reading Ks/Vs
    if (kt < 31) STAGE(k0 + 64);  // restage freed single buffer
  }
#undef STAGE

  // ---- normalize and store X[b,s,h*64+d] (f16) ----
#pragma unroll
  for (int bb = 0; bb < 2; ++bb) {
    const float inv = 1.0f / lrow[bb];
    float invq[4];
#pragma unroll
    for (int j = 0; j < 4; ++j) invq[j] = __shfl(inv, l4 * 4 + j);
#pragma unroll
    for (int j = 0; j < 4; ++j) {
      const int qrow = q0 + l4 * 4 + j;
#pragma unroll
      for (int n = 0; n < 4; ++n)
        X[((size_t)bb * 2048 + qrow) * 1024 + h * 64 + n * 16 + l15] =
            (f16)(oacc[bb][n][j] * invq[j]);
    }
  }
}

// ---------------- host ------------------------------------------------------
extern "C" void kernel_launch(void* const* d_in, const int* in_sizes, int n_in,
                              void* d_out, int out_size, void* d_ws, size_t ws_size,
                              hipStream_t stream) {
  const float* query = (const float*)d_in[0];
  const float* key_ = (const float*)d_in[1];
  const float* value = (const float*)d_in[2];
  const uint8_t* mask = (const uint8_t*)d_in[3];
  const float* bias = (const float*)d_in[4];
  const float* Wq = (const float*)d_in[5];
  const float* bq = (const float*)d_in[6];
  const float* Wk = (const float*)d_in[7];
  const float* bk = (const float*)d_in[8];
  const float* Wv = (const float*)d_in[9];
  const float* bv = (const float*)d_in[10];
  const float* Wo = (const float*)d_in[11];
  const float* bo = (const float*)d_in[12];

  char* p = (char*)d_ws;
  f16* qh = (f16*)p; p += (size_t)4194304 * 2;   // contiguous cvt dst region:
  f16* kh = (f16*)p; p += (size_t)4194304 * 2;   // qh,kh,vh,wqh,wkh,wvh,woh
  f16* vh = (f16*)p; p += (size_t)4194304 * 2;
  f16* wqh = (f16*)p; p += (size_t)1048576 * 2;
  f16* wkh = (f16*)p; p += (size_t)1048576 * 2;
  f16* wvh = (f16*)p; p += (size_t)1048576 * 2;
  f16* woh = (f16*)p; p += (size_t)1048576 * 2;
  f16* Qp = (f16*)p; p += (size_t)4194304 * 2;
  f16* Kp = (f16*)p; p += (size_t)4194304 * 2;
  f16* Vt = (f16*)p; p += (size_t)4194304 * 2;
  f16* Xh = (f16*)p; p += (size_t)4194304 * 2;
  uint8_t* m8 = (uint8_t*)p; p += (size_t)8388608;
  int* flag = (int*)p; p += 256;
  if (ws_size < (size_t)(p - (char*)d_ws)) return;

  mask_detect<<<1, 256, 0, stream>>>(mask, flag);
  mask_canon<<<8192, 256, 0, stream>>>(mask, m8, flag);

  CvtSrcs cs;
  cs.s[0] = query; cs.s[1] = key_; cs.s[2] = value;
  cs.s[3] = Wq; cs.s[4] = Wk; cs.s[5] = Wv; cs.s[6] = Wo;
  cvt_all<<<16384, 256, 0, stream>>>(cs, qh);

  gemm_qkv<<<1536, 256, 0, stream>>>(qh, kh, vh, wqh, wkh, wvh, bq, bk, bv,
                                     Qp, Kp, Vt);

  attn_fwd<<<512, 256, 0, stream>>>(Qp, Kp, Vt, bias, m8, Xh);

  gemm_out<<<512, 256, 0, stream>>>(Xh, woh, bo, (float*)d_out);
}